// Round 5
// baseline (135.076 us; speedup 1.0000x reference)
//
#include <hip/hip_runtime.h>

// Ring-lattice sheaf Laplacian builder: N=50000 nodes, strides 1..16, d=4.
// d_out is FLOAT32, outputs concatenated flat (element offsets):
//   edge_index rows [0, 26.4M) | cols [26.4M, 52.8M)
//   weights         [52.8M, 79.2M)
//   saved_tril_maps [79.2M, 92.0M)
#define NN 50000
#define DG 16
#define EM 800000
#define OFF_COLS 26400000
#define OFF_W    52800000
#define OFF_TRIL 79200000
#define NIDX 6600000
#define NW4  6600000      // weights float4 count

#define NB_E 3125         // ceil(EM/256)
#define NB_D 196          // ceil(NN/256)
#define NB_W 25782        // ceil(NW4/256)
#define NB_I 25782        // ceil(NIDX/256)

typedef unsigned int  u32;
typedef long long ll64;
typedef float f4v __attribute__((ext_vector_type(4)));

__device__ __forceinline__ void nt_store4(float* p, float a, float b, float c, float d) {
    f4v v = {a, b, c, d};
    __builtin_nontemporal_store(v, (f4v*)p);
}

// ---- bf16 unpack (maps may be bf16-packed) ----
__device__ __forceinline__ void unpack8(uint4 v, float* f) {
    f[0] = __uint_as_float(v.x << 16); f[1] = __uint_as_float(v.x & 0xffff0000u);
    f[2] = __uint_as_float(v.y << 16); f[3] = __uint_as_float(v.y & 0xffff0000u);
    f[4] = __uint_as_float(v.z << 16); f[5] = __uint_as_float(v.z & 0xffff0000u);
    f[6] = __uint_as_float(v.w << 16); f[7] = __uint_as_float(v.w & 0xffff0000u);
}

// rank of node v within sorted({u} U {u +- s mod N, s=1..16}); 33 distinct values.
__device__ __forceinline__ int brank(int u, int v) {
    int a0 = u - DG; if (a0 < 0) a0 += NN;
    if (a0 <= NN - 33) return v - a0;
    int k = a0 + 33 - NN;
    return (v < k) ? v : k + (v - a0);
}

// ---- dtype-flexible input loads ----
template<bool F32M>
__device__ __forceinline__ void load_map(const void* maps, size_t e, float* F) {
    if (F32M) {
        const float4* p = (const float4*)maps;
        float4 a = p[e*4+0], b = p[e*4+1], c = p[e*4+2], d = p[e*4+3];
        F[0]=a.x; F[1]=a.y; F[2]=a.z; F[3]=a.w;
        F[4]=b.x; F[5]=b.y; F[6]=b.z; F[7]=b.w;
        F[8]=c.x; F[9]=c.y; F[10]=c.z; F[11]=c.w;
        F[12]=d.x; F[13]=d.y; F[14]=d.z; F[15]=d.w;
    } else {
        const uint4* p = (const uint4*)maps;
        unpack8(p[e*2], F); unpack8(p[e*2+1], F + 8);
    }
}
template<bool I64>
__device__ __forceinline__ int ld_idx(const void* p, size_t i) {
    return I64 ? (int)((const ll64*)p)[i] : ((const int*)p)[i];
}

// ---- inline detection (uniform scalar loads; ~free) ----
__device__ __forceinline__ void detect(const u32* __restrict__ mw,
                                       const u32* __restrict__ lw,
                                       int& i64, int& f32m) {
    u32 odd = lw[1] | lw[3] | lw[5] | lw[7];
    i64 = (odd == 0u) ? 1 : 0;
    int sane = 0;
#pragma unroll
    for (int i = 0; i < 32; ++i) {
        u32 ex = (mw[i] >> 7) & 0xFFu;
        sane += (ex >= 0x70u && ex <= 0x87u) ? 1 : 0;
    }
    f32m = (sane < 16) ? 1 : 0;
}

// ---- edges: T = -L^T R -> saved_tril_maps only (contiguous, cached stores) ----
template<bool I64, bool F32M>
__device__ __forceinline__ void edges_body(int m, const void* maps, const void* li_,
                                           const void* ri_, float* __restrict__ out) {
    int li = ld_idx<I64>(li_, m), ri = ld_idx<I64>(ri_, m);
    float L[16], R[16];
    load_map<F32M>(maps, (size_t)li, L);
    load_map<F32M>(maps, (size_t)ri, R);
    float T[16];
#pragma unroll
    for (int x = 0; x < 4; ++x)
#pragma unroll
        for (int y = 0; y < 4; ++y)
            T[x*4+y] = -(L[x]*R[y] + L[4+x]*R[4+y] + L[8+x]*R[8+y] + L[12+x]*R[12+y]);
    float4* tp = (float4*)(out + OFF_TRIL) + (size_t)m * 4;
    tp[0] = make_float4(T[0],  T[1],  T[2],  T[3]);
    tp[1] = make_float4(T[4],  T[5],  T[6],  T[7]);
    tp[2] = make_float4(T[8],  T[9],  T[10], T[11]);
    tp[3] = make_float4(T[12], T[13], T[14], T[15]);
}

// ---- diag: per node, sum of F^T F over 32 outgoing directed edges ----
template<bool F32M, bool USEWS>
__device__ __forceinline__ void diag_body(int u, const void* maps,
                                          float* __restrict__ out, float* __restrict__ ws) {
    float acc[16];
#pragma unroll
    for (int i = 0; i < 16; ++i) acc[i] = 0.f;
#pragma unroll 4
    for (int s = 1; s <= DG; ++s) {             // e = u*16 + s-1 (src=u)
        float F[16]; load_map<F32M>(maps, (size_t)u*DG + (s-1), F);
#pragma unroll
        for (int x = 0; x < 4; ++x)
#pragma unroll
            for (int y = 0; y < 4; ++y)
                acc[x*4+y] += F[x]*F[y] + F[4+x]*F[4+y] + F[8+x]*F[8+y] + F[12+x]*F[12+y];
    }
#pragma unroll 4
    for (int s = 1; s <= DG; ++s) {             // e = M + ((u-s)%N)*16 + s-1 (src=u)
        int w = u - s; if (w < 0) w += NN;
        float F[16]; load_map<F32M>(maps, (size_t)EM + (size_t)w*DG + (s-1), F);
#pragma unroll
        for (int x = 0; x < 4; ++x)
#pragma unroll
            for (int y = 0; y < 4; ++y)
                acc[x*4+y] += F[x]*F[y] + F[4+x]*F[4+y] + F[8+x]*F[8+y] + F[12+x]*F[12+y];
    }
    if (USEWS) {
        float4* d = (float4*)(ws + (size_t)u * 16);
#pragma unroll
        for (int x = 0; x < 4; ++x)
            d[x] = make_float4(acc[x*4], acc[x*4+1], acc[x*4+2], acc[x*4+3]);
    } else {
        int r = brank(u, u);
        float* wd = out + OFF_W + (size_t)u*528 + r*4;
#pragma unroll
        for (int x = 0; x < 4; ++x)
            *((float4*)(wd + x*132)) = make_float4(acc[x*4], acc[x*4+1], acc[x*4+2], acc[x*4+3]);
    }
}

// ---- kernel 1: edges -> tril, diag -> ws (or final slots) ----
template<bool USEWS>
__global__ void k1(const void* __restrict__ maps, const void* __restrict__ li_,
                   const void* __restrict__ ri_, float* __restrict__ out,
                   float* __restrict__ ws) {
    int blk = blockIdx.x;
    if (blk < NB_E) {
        int m = blk * 256 + threadIdx.x;
        if (m >= EM) return;
        int i6, f3;
        detect((const u32*)maps, (const u32*)li_, i6, f3);
        if (i6) { if (f3) edges_body<true ,true >(m, maps, li_, ri_, out);
                  else    edges_body<true ,false>(m, maps, li_, ri_, out); }
        else    { if (f3) edges_body<false,true >(m, maps, li_, ri_, out);
                  else    edges_body<false,false>(m, maps, li_, ri_, out); }
    } else {
        int u = (blk - NB_E) * 256 + threadIdx.x;
        if (u >= NN) return;
        int i6, f3;
        detect((const u32*)maps, (const u32*)li_, i6, f3);
        if (f3) diag_body<true , USEWS>(u, maps, out, ws);
        else    diag_body<false, USEWS>(u, maps, out, ws);
    }
}

// ---- idx: edge_index rows/cols, pure function of output position ----
__device__ __forceinline__ void idx_body(int t, float* __restrict__ out) {
    int u = t / 132;
    int q = t - u * 132;
    int i = q / 33;
    int bb = q - i * 33;
    int a0 = u - DG; if (a0 < 0) a0 += NN;
    int v;
    if (a0 <= NN - 33) v = a0 + bb;
    else { int k = a0 + 33 - NN; v = (bb < k) ? bb : a0 + (bb - k); }
    float rf = (float)(u * 4 + i);
    float c0 = (float)(v * 4);
    nt_store4(out + (size_t)t*4,            rf, rf,       rf,       rf);
    nt_store4(out + OFF_COLS + (size_t)t*4, c0, c0 + 1.f, c0 + 2.f, c0 + 3.f);
}

// ---- kernel 2: weights assembly (coalesced nt) then idx ----
template<bool USEWS>
__global__ void k2(float* __restrict__ out, const float* __restrict__ ws) {
    int blk = blockIdx.x;
    if (blk < NB_W) {
        int t = blk * 256 + threadIdx.x;
        if (t >= NW4) return;
        int u = t / 132;
        int g = t - u * 132;
        int r = g / 33;
        int c = g - r * 33;
        // rank -> neighbor node v
        int v;
        if (u >= 16 && u <= NN - 17) v = u - 16 + c;
        else {
            int a0h = u - 16; if (a0h < 0) a0h += NN;
            int k = a0h + 33 - NN;
            v = (c < k) ? c : a0h + (c - k);
        }
        float4 val;
        if (v == u) {
            // staged diag (ws) or previously-written final slot (same address)
            const float* src = USEWS ? (ws + (size_t)u*16 + r*4)
                                     : (out + OFF_W + (size_t)t*4);
            val = *((const float4*)src);
        } else {
            int bm = (v < u) ? v : u;
            int am = (v < u) ? u : v;
            int m;
            if (am - bm <= 16) {                 // no-wrap pair: left edge 2nd-half
                int ex = bm - (NN - 16);
                int corr = (ex > 0) ? (ex * (ex + 1)) / 2 : 0;
                m = 136 + bm*16 + (am - bm - 1) - corr;
            } else {                             // wrap pair: left edge 1st-half
                int ja = am - (NN - 16);
                m = (ja * (ja + 1)) / 2 + bm;
            }
            const float* tb = out + OFF_TRIL + (size_t)m * 16;
            if (v < u) val = *((const float4*)(tb + r*4));     // block = T, row r
            else       val = make_float4(tb[r], tb[4+r], tb[8+r], tb[12+r]); // T^T
        }
        nt_store4(out + OFF_W + (size_t)t*4, val.x, val.y, val.z, val.w);
    } else {
        int t = (blk - NB_W) * 256 + threadIdx.x;
        if (t >= NIDX) return;
        idx_body(t, out);
    }
}

extern "C" void kernel_launch(void* const* d_in, const int* in_sizes, int n_in,
                              void* d_out, int out_size, void* d_ws, size_t ws_size,
                              hipStream_t stream) {
    const void* maps = d_in[0];
    const void* li   = d_in[1];
    const void* ri   = d_in[2];
    float* out = (float*)d_out;
    float* ws  = (float*)d_ws;
    bool usews = (ws_size >= (size_t)NN * 16 * sizeof(float));
    if (usews) {
        k1<true ><<<NB_E + NB_D, 256, 0, stream>>>(maps, li, ri, out, ws);
        k2<true ><<<NB_W + NB_I, 256, 0, stream>>>(out, ws);
    } else {
        k1<false><<<NB_E + NB_D, 256, 0, stream>>>(maps, li, ri, out, ws);
        k2<false><<<NB_W + NB_I, 256, 0, stream>>>(out, ws);
    }
}

// Round 6
// 91.663 us; speedup vs baseline: 1.4736x; 1.4736x over previous
//
#include <hip/hip_runtime.h>

// Ring-lattice sheaf Laplacian builder: N=50000 nodes, strides 1..16, d=4.
// d_out is FLOAT32, outputs concatenated flat (element offsets):
//   edge_index rows [0, 26.4M) | cols [26.4M, 52.8M)
//   weights         [52.8M, 79.2M)
//   saved_tril_maps [79.2M, 92.0M)
#define NN 50000
#define DG 16
#define EM 800000
#define OFF_COLS 26400000
#define OFF_W    52800000
#define OFF_TRIL 79200000
#define NIDX 6600000

#define NPB 8              // nodes per block (8*32 = 256 threads)
#define NB_N 6250          // 50000/8 node blocks
#define NB_I 25782         // ceil(NIDX/256) idx blocks
#define LSTRIDE 544        // LDS floats per node (528 + pad)

typedef unsigned int u32;
typedef float f4v __attribute__((ext_vector_type(4)));

__device__ __forceinline__ void nt_store4(float* p, float a, float b, float c, float d) {
    f4v v = {a, b, c, d};
    __builtin_nontemporal_store(v, (f4v*)p);
}

// ---- bf16 unpack (maps may be bf16-packed) ----
__device__ __forceinline__ void unpack8(uint4 v, float* f) {
    f[0] = __uint_as_float(v.x << 16); f[1] = __uint_as_float(v.x & 0xffff0000u);
    f[2] = __uint_as_float(v.y << 16); f[3] = __uint_as_float(v.y & 0xffff0000u);
    f[4] = __uint_as_float(v.z << 16); f[5] = __uint_as_float(v.z & 0xffff0000u);
    f[6] = __uint_as_float(v.w << 16); f[7] = __uint_as_float(v.w & 0xffff0000u);
}

// rank of node v within sorted({u} U {u +- s mod N, s=1..16}); 33 distinct values.
__device__ __forceinline__ int brank(int u, int v) {
    int a0 = u - DG; if (a0 < 0) a0 += NN;
    if (a0 <= NN - 33) return v - a0;
    int k = a0 + 33 - NN;
    return (v < k) ? v : k + (v - a0);
}

template<bool F32M>
__device__ __forceinline__ void load_map(const void* maps, size_t e, float* F) {
    if (F32M) {
        const float4* p = (const float4*)maps;
        float4 a = p[e*4+0], b = p[e*4+1], c = p[e*4+2], d = p[e*4+3];
        F[0]=a.x; F[1]=a.y; F[2]=a.z; F[3]=a.w;
        F[4]=b.x; F[5]=b.y; F[6]=b.z; F[7]=b.w;
        F[8]=c.x; F[9]=c.y; F[10]=c.z; F[11]=c.w;
        F[12]=d.x; F[13]=d.y; F[14]=d.z; F[15]=d.w;
    } else {
        const uint4* p = (const uint4*)maps;
        unpack8(p[e*2], F); unpack8(p[e*2+1], F + 8);
    }
}

// maps dtype sniff: low-16 halves as bf16 rarely have sane exponents if raw f32
__device__ __forceinline__ int detect_f32(const u32* __restrict__ mw) {
    int sane = 0;
#pragma unroll
    for (int i = 0; i < 32; ++i) {
        u32 ex = (mw[i] >> 7) & 0xFFu;
        sane += (ex >= 0x70u && ex <= 0x87u) ? 1 : 0;
    }
    return (sane < 16) ? 1 : 0;
}

// ---- node-centric: 32 threads per node; thread = one neighbor pair ----
template<bool F32M>
__device__ __forceinline__ void node_body(int blk, int tid, const void* maps,
                                          float* __restrict__ out, float* lds) {
    int k = tid >> 5, s = tid & 31;
    int u = blk * NPB + k;                       // < NN exactly
    int cd = brank(u, u);                        // diag rank (16 for interior)
    int c = s + (s >= cd ? 1 : 0);               // this thread's off-diag rank
    // rank-inverse -> neighbor v
    int a0 = u - DG; if (a0 < 0) a0 += NN;
    int v;
    if (a0 <= NN - 33) v = a0 + c;
    else { int kk = a0 + 33 - NN; v = (c < kk) ? c : a0 + (c - kk); }
    // pair (bm, am), analytic directed-edge ids + tril index
    int bm = (u < v) ? u : v, am = (u < v) ? v : u;
    int dnw = am - bm;
    size_t eL, eR; int mtr;
    if (dnw <= DG) {                             // no-wrap pair
        eL = (size_t)EM + (size_t)bm * DG + (dnw - 1);   // am->bm (2nd half)
        eR = (size_t)bm * DG + (dnw - 1);                // bm->am (1st half)
        int ex = bm - (NN - DG);
        int corr = (ex > 0) ? ex * (ex + 1) / 2 : 0;
        mtr = 136 + bm * DG + (dnw - 1) - corr;
    } else {                                     // wrap pair
        int dp = NN - dnw;
        eL = (size_t)am * DG + (dp - 1);                 // am->bm (1st half)
        eR = (size_t)EM + (size_t)am * DG + (dp - 1);    // bm->am (2nd half)
        int ja = am - (NN - DG);
        mtr = ja * (ja + 1) / 2 + bm;
    }
    float L[16], R[16];
    load_map<F32M>(maps, eL, L);
    load_map<F32M>(maps, eR, R);
    float T[16];
#pragma unroll
    for (int x = 0; x < 4; ++x)
#pragma unroll
        for (int y = 0; y < 4; ++y)
            T[x*4+y] = -(L[x]*R[y] + L[4+x]*R[4+y] + L[8+x]*R[8+y] + L[12+x]*R[12+y]);
    // diag contribution: outgoing map u->v (already in registers)
    const float* F = (u == am) ? L : R;
    float P[16];
#pragma unroll
    for (int x = 0; x < 4; ++x)
#pragma unroll
        for (int y = 0; y < 4; ++y)
            P[x*4+y] = F[x]*F[y] + F[4+x]*F[4+y] + F[8+x]*F[8+y] + F[12+x]*F[12+y];
    // butterfly sum across the node's 32 lanes (stays within half-wave)
#pragma unroll
    for (int msk = 1; msk < 32; msk <<= 1)
#pragma unroll
        for (int j = 0; j < 16; ++j)
            P[j] += __shfl_xor(P[j], msk, 64);
    // stage this node's row-image in LDS (output layout: (x, c*4+y))
    float* nb = lds + k * LSTRIDE;
    if (u == am) {                               // block (u,v) = T
#pragma unroll
        for (int x = 0; x < 4; ++x)
            *(f4v*)(nb + x*132 + c*4) = (f4v){T[x*4], T[x*4+1], T[x*4+2], T[x*4+3]};
        // saved_tril_maps[mtr]: one full 64B line, written once per pair
        float* tp = out + OFF_TRIL + (size_t)mtr * 16;
        nt_store4(tp + 0,  T[0],  T[1],  T[2],  T[3]);
        nt_store4(tp + 4,  T[4],  T[5],  T[6],  T[7]);
        nt_store4(tp + 8,  T[8],  T[9],  T[10], T[11]);
        nt_store4(tp + 12, T[12], T[13], T[14], T[15]);
    } else {                                     // block (u,v) = T^T
#pragma unroll
        for (int x = 0; x < 4; ++x)
            *(f4v*)(nb + x*132 + c*4) = (f4v){T[x], T[4+x], T[8+x], T[12+x]};
    }
    if (s == 0) {                                // diag block at rank cd
#pragma unroll
        for (int x = 0; x < 4; ++x)
            *(f4v*)(nb + x*132 + cd*4) = (f4v){P[x*4], P[x*4+1], P[x*4+2], P[x*4+3]};
    }
    __syncthreads();
    // stream 8 nodes x 528 floats = 1056 float4, fully coalesced nt
    float* wbase = out + OFF_W + (size_t)blk * (NPB * 528);
#pragma unroll
    for (int i = 0; i < 5; ++i) {
        int id = i * 256 + tid;
        if (id < 1056) {
            int n2 = id / 132, j = id - n2 * 132;
            f4v val = *(f4v*)(lds + n2 * LSTRIDE + j * 4);
            __builtin_nontemporal_store(val, (f4v*)(wbase + (size_t)id * 4));
        }
    }
}

// ---- idx: edge_index rows/cols, pure function of output position ----
__device__ __forceinline__ void idx_body(int t, float* __restrict__ out) {
    int u = t / 132;
    int q = t - u * 132;
    int i = q / 33;
    int bb = q - i * 33;
    int a0 = u - DG; if (a0 < 0) a0 += NN;
    int v;
    if (a0 <= NN - 33) v = a0 + bb;
    else { int k = a0 + 33 - NN; v = (bb < k) ? bb : a0 + (bb - k); }
    float rf = (float)(u * 4 + i);
    float c0 = (float)(v * 4);
    nt_store4(out + (size_t)t*4,            rf, rf,       rf,       rf);
    nt_store4(out + OFF_COLS + (size_t)t*4, c0, c0 + 1.f, c0 + 2.f, c0 + 3.f);
}

__global__ void __launch_bounds__(256) k_fused(const void* __restrict__ maps,
                                               float* __restrict__ out) {
    __shared__ float lds[NPB * LSTRIDE];
    int blk = blockIdx.x;
    if (blk < NB_N) {
        // bijective chunked XCD swizzle (NB_N = 8*781 + 2)
        int xcd = blk & 7, i = blk >> 3;
        const int q = NB_N >> 3, r = NB_N & 7;
        int nb = (xcd < r ? xcd * (q + 1) : r * (q + 1) + (xcd - r) * q) + i;
        int f3 = detect_f32((const u32*)maps);
        if (f3) node_body<true >(nb, threadIdx.x, maps, out, lds);
        else    node_body<false>(nb, threadIdx.x, maps, out, lds);
    } else {
        int t = (blk - NB_N) * 256 + threadIdx.x;
        if (t >= NIDX) return;
        idx_body(t, out);
    }
}

extern "C" void kernel_launch(void* const* d_in, const int* in_sizes, int n_in,
                              void* d_out, int out_size, void* d_ws, size_t ws_size,
                              hipStream_t stream) {
    const void* maps = d_in[0];           // index arrays d_in[1..3] no longer needed
    float* out = (float*)d_out;
    k_fused<<<NB_N + NB_I, 256, 0, stream>>>(maps, out);
}